// Round 5
// baseline (255.595 us; speedup 1.0000x reference)
//
#include <hip/hip_runtime.h>

#define LQ 4096
#define CH 128
#define NB 4
// log2(e)/sqrt(128): folded into Q so softmax = exp2(S)
#define QSCALE 0.12753139626233174f
#define ASTR 136    // tileA row stride (hw): 128 c + 8 pad
#define BSTR 72     // tileB row stride (hw): 64 t + 8 pad
#define MAXCH 8

typedef __attribute__((ext_vector_type(8))) unsigned short ushort8;
typedef __attribute__((ext_vector_type(4))) unsigned short ushort4v;
typedef __attribute__((ext_vector_type(8))) __bf16 bf16x8;
typedef __attribute__((ext_vector_type(4))) float f32x4;

__device__ inline unsigned short f2bf(float f) {
    unsigned int u = __builtin_bit_cast(unsigned int, f);
    u += 0x7fffu + ((u >> 16) & 1u);   // round-to-nearest-even
    return (unsigned short)(u >> 16);
}
__device__ inline float bf2f(unsigned short h) {
    unsigned int u = (unsigned int)h << 16;
    return __builtin_bit_cast(float, u);
}
// pack two positive floats to bf16 pair, round-half-up (2 adds+shift+and+or)
__device__ inline unsigned int bfpack2(float a, float b) {
    unsigned int ua = __builtin_bit_cast(unsigned int, a) + 0x8000u;
    unsigned int ub = __builtin_bit_cast(unsigned int, b) + 0x8000u;
    return (ua >> 16) | (ub & 0xffff0000u);
}

// ---------------------------------------------------------------------------
// Kernel 1: v = W_kv @ x (+bias); emit bf16 Vt[b][t][c] and Vc[b][c][t].
// 512 blocks: (b, 64-l tile, o-half). W rows wave-uniform -> s_load broadcast.
// ---------------------------------------------------------------------------
__global__ __launch_bounds__(256) void prep_kernel(
    const float* __restrict__ x, const float* __restrict__ Wkv,
    const float* __restrict__ bkv,
    unsigned short* __restrict__ Vt, unsigned short* __restrict__ Vc)
{
    __shared__ unsigned short vs[64 * 64];   // [o_local][l] 8 KB
    const int tid = threadIdx.x;
    const int lane = tid & 63;
    const int b = blockIdx.x & 3;
    const int l0 = ((blockIdx.x >> 2) & 63) << 6;
    const int ohalf = blockIdx.x >> 8;              // 0/1
    const int o0l = __builtin_amdgcn_readfirstlane((tid >> 6) << 4);

    float xr[CH];   // x[:, l0+lane], coalesced loads
    #pragma unroll
    for (int c = 0; c < CH; ++c)
        xr[c] = x[((size_t)b * CH + c) * LQ + l0 + lane];

    for (int oo = 0; oo < 16; oo += 2) {
        const int ol = o0l + oo;
        const int o = ohalf * 64 + ol;
        const float* wr0 = Wkv + (size_t)o * CH;    // uniform -> s_load
        const float* wr1 = wr0 + CH;
        float p0[4] = {bkv[o], 0.f, 0.f, 0.f};
        float p1[4] = {bkv[o + 1], 0.f, 0.f, 0.f};
        #pragma unroll
        for (int c = 0; c < CH; c += 4) {
            #pragma unroll
            for (int k = 0; k < 4; ++k) {
                p0[k] += wr0[c + k] * xr[c + k];
                p1[k] += wr1[c + k] * xr[c + k];
            }
        }
        const float a0 = (p0[0] + p0[1]) + (p0[2] + p0[3]);
        const float a1 = (p1[0] + p1[1]) + (p1[2] + p1[3]);
        const unsigned short h0 = f2bf(a0), h1 = f2bf(a1);
        Vc[((size_t)b * CH + o) * LQ + l0 + lane] = h0;
        Vc[((size_t)b * CH + o + 1) * LQ + l0 + lane] = h1;
        vs[ol * 64 + lane] = h0;
        vs[(ol + 1) * 64 + lane] = h1;
    }
    __syncthreads();
    #pragma unroll
    for (int i = 0; i < 2; ++i) {
        const int idx = i * 256 + tid;        // l(64) x og(8)
        const int l = idx >> 3, og = idx & 7;
        ushort8 v;
        #pragma unroll
        for (int k = 0; k < 8; ++k) v[k] = vs[(og * 8 + k) * 64 + l];
        *(ushort8*)(Vt + ((size_t)b * LQ + l0 + l) * CH + ohalf * 64 + og * 8) = v;
    }
}

// ---------------------------------------------------------------------------
// Kernel 2: flash attention, split-K, LDS-staged tiles, transposed-S chain:
// S^T = mfma(A=V, B=Q) -> C-layout q=l16,t=quad*4+r -> exp2 -> packed directly
// as zero-padded A-operand of PV mfma (no P LDS round-trip). PV B-frags are
// ds_read_b64 from tileB with explicit zero high halves.
// ---------------------------------------------------------------------------
__global__ __launch_bounds__(256, 3) void attn_kernel(
    const float* __restrict__ x, const unsigned short* __restrict__ Vt,
    const unsigned short* __restrict__ Vc,
    unsigned short* __restrict__ Opart, float* __restrict__ Lsum, int titers)
{
    __shared__ __align__(16) unsigned short tileA[64 * ASTR];      // 17408 B
    __shared__ __align__(16) unsigned short tileB[128 * BSTR];     // 18432 B
    const int tid = threadIdx.x;
    const int wave = tid >> 6, lane = tid & 63;
    const int quad = lane >> 4, l16 = lane & 15;
    const int b = blockIdx.x & 3;          // XCD k gets b = k%4 -> V L2-resident
    const int rest = blockIdx.x >> 2;
    const int qtile = rest & 31;           // 32 tiles of 128 q
    const int chunk = rest >> 5;
    const int q0w = (qtile << 7) + (wave << 5);
    const int tbase = chunk * titers * 64;

    const unsigned short* vtb = Vt + (size_t)b * LQ * CH;
    const unsigned short* vcb = Vc + (size_t)b * CH * LQ;

    // Q B-frags from x: B[n=l16 -> q][k=quad*8+j -> c], scaled (one-time)
    bf16x8 qf[2][4];
    #pragma unroll
    for (int mt = 0; mt < 2; ++mt)
        #pragma unroll
        for (int kc = 0; kc < 4; ++kc) {
            ushort8 v;
            #pragma unroll
            for (int j = 0; j < 8; ++j) {
                int c = kc * 32 + quad * 8 + j;
                v[j] = f2bf(x[((size_t)b * CH + c) * LQ + q0w + mt * 16 + l16] * QSCALE);
            }
            qf[mt][kc] = __builtin_bit_cast(bf16x8, v);
        }

    f32x4 oacc[2][8];
    #pragma unroll
    for (int mt = 0; mt < 2; ++mt)
        #pragma unroll
        for (int i = 0; i < 8; ++i) oacc[mt][i] = f32x4{0.f, 0.f, 0.f, 0.f};
    float lsum[2] = {0.f, 0.f};

    // prologue: prefetch tile 0 into registers (coalesced dwordx4)
    ushort8 RA[4], RB[4];
    {
        const int t0 = tbase;
        #pragma unroll
        for (int i = 0; i < 4; ++i) {
            const int ci = i * 256 + tid;
            RA[i] = *(const ushort8*)(vtb + (size_t)(t0 + (ci >> 4)) * CH + (ci & 15) * 8);
        }
        #pragma unroll
        for (int i = 0; i < 4; ++i) {
            const int ci = i * 256 + tid;
            RB[i] = *(const ushort8*)(vcb + (size_t)(ci >> 3) * LQ + t0 + (ci & 7) * 8);
        }
    }

    for (int it = 0; it < titers; ++it) {
        __syncthreads();   // all waves done reading LDS tiles (no-op at it=0)
        #pragma unroll
        for (int i = 0; i < 4; ++i) {
            const int ci = i * 256 + tid;
            *(ushort8*)(tileA + (ci >> 4) * ASTR + (ci & 15) * 8) = RA[i];
        }
        #pragma unroll
        for (int i = 0; i < 4; ++i) {
            const int ci = i * 256 + tid;
            *(ushort8*)(tileB + (ci >> 3) * BSTR + (ci & 7) * 8) = RB[i];
        }
        __syncthreads();   // staged tile visible
        // issue next-tile prefetch NOW (~full compute phase to cover latency)
        {
            const int t0n = (it + 1 < titers) ? tbase + (it + 1) * 64 : tbase;
            #pragma unroll
            for (int i = 0; i < 4; ++i) {
                const int ci = i * 256 + tid;
                RA[i] = *(const ushort8*)(vtb + (size_t)(t0n + (ci >> 4)) * CH + (ci & 15) * 8);
            }
            #pragma unroll
            for (int i = 0; i < 4; ++i) {
                const int ci = i * 256 + tid;
                RB[i] = *(const ushort8*)(vcb + (size_t)(ci >> 3) * LQ + t0n + (ci & 7) * 8);
            }
        }
        // per 16-key sub-tile nt: S^T -> exp2 -> PV (P stays in registers)
        #pragma unroll
        for (int nt = 0; nt < 4; ++nt) {
            // A-frags: V[t=nt*16+l16][c=kc*32+quad*8+j] from tileA (b128)
            bf16x8 vA[4];
            #pragma unroll
            for (int kc = 0; kc < 4; ++kc)
                vA[kc] = __builtin_bit_cast(bf16x8,
                    *(const ushort8*)(tileA + (nt * 16 + l16) * ASTR + kc * 32 + quad * 8));
            // S^T tiles: D[m=t][n=q]; lane: q=l16, t=nt*16+quad*4+r
            f32x4 s[2];
            #pragma unroll
            for (int mt = 0; mt < 2; ++mt) {
                s[mt] = f32x4{0.f, 0.f, 0.f, 0.f};
                #pragma unroll
                for (int kc = 0; kc < 4; ++kc)
                    s[mt] = __builtin_amdgcn_mfma_f32_16x16x32_bf16(vA[kc], qf[mt][kc], s[mt], 0, 0, 0);
            }
            // exp2 + pack directly into zero-padded PV A-frags
            bf16x8 pf[2];
            #pragma unroll
            for (int mt = 0; mt < 2; ++mt) {
                float p0 = __builtin_amdgcn_exp2f(s[mt][0]);
                float p1 = __builtin_amdgcn_exp2f(s[mt][1]);
                float p2 = __builtin_amdgcn_exp2f(s[mt][2]);
                float p3 = __builtin_amdgcn_exp2f(s[mt][3]);
                lsum[mt] += (p0 + p1) + (p2 + p3);
                unsigned int lo = bfpack2(p0, p1);
                unsigned int hi = bfpack2(p2, p3);
                ushort8 pk;
                pk[0] = (unsigned short)lo; pk[1] = (unsigned short)(lo >> 16);
                pk[2] = (unsigned short)hi; pk[3] = (unsigned short)(hi >> 16);
                pk[4] = 0; pk[5] = 0; pk[6] = 0; pk[7] = 0;
                pf[mt] = __builtin_bit_cast(bf16x8, pk);
            }
            // PV: B[k=quad*8+j][n=c=l16] = V[t=nt*16+quad*4+j][c], j<4; 0 else
            #pragma unroll
            for (int nc = 0; nc < 8; ++nc) {
                ushort4v d = *(const ushort4v*)(tileB +
                    (nc * 16 + l16) * BSTR + nt * 16 + quad * 4);
                ushort8 vb;
                vb[0] = d[0]; vb[1] = d[1]; vb[2] = d[2]; vb[3] = d[3];
                vb[4] = 0; vb[5] = 0; vb[6] = 0; vb[7] = 0;
                bf16x8 vB = __builtin_bit_cast(bf16x8, vb);
                #pragma unroll
                for (int mt = 0; mt < 2; ++mt)
                    oacc[mt][nc] = __builtin_amdgcn_mfma_f32_16x16x32_bf16(pf[mt], vB, oacc[mt][nc], 0, 0, 0);
            }
        }
    }
    // ---- Lsum: reduce per-lane partial (q=l16) across the 4 quads ----
    const size_t pbase = ((size_t)(chunk * NB + b) * LQ);
    #pragma unroll
    for (int mt = 0; mt < 2; ++mt) {
        float v = lsum[mt];
        v += __shfl_xor(v, 16);
        v += __shfl_xor(v, 32);
        if (lane < 16) Lsum[pbase + q0w + mt * 16 + lane] = v;
    }
    // ---- write partials: Opart[ch][b][q][c] (bf16); oacc lane: q=quad*4+r, c=l16
    #pragma unroll
    for (int mt = 0; mt < 2; ++mt)
        #pragma unroll
        for (int r = 0; r < 4; ++r) {
            const int q = q0w + mt * 16 + quad * 4 + r;
            unsigned short* orow = Opart + (pbase + q) * CH + l16;
            #pragma unroll
            for (int nc = 0; nc < 8; ++nc) orow[nc * 16] = f2bf(oacc[mt][nc][r]);
        }
}

// ---------------------------------------------------------------------------
// Kernel 3: out[b][c][q] = sum_ch Opart[ch][b][q][c] / sum_ch Lsum[ch][b][q]
// 512 blocks: (b, 32-q tile). LDS transpose.
// ---------------------------------------------------------------------------
__global__ __launch_bounds__(256) void combine_kernel(
    const unsigned short* __restrict__ Opart, const float* __restrict__ Lsum,
    float* __restrict__ out, int nchunk)
{
    __shared__ __align__(16) float ls[32 * 132];   // [q][c] padded
    __shared__ float linv[32];
    const int tid = threadIdx.x;
    const int b = blockIdx.x & 3;
    const int q0 = (blockIdx.x >> 2) << 5;

    if (tid < 32) {
        float s = 0.f;
        for (int ch = 0; ch < nchunk; ++ch) s += Lsum[(size_t)(ch * NB + b) * LQ + q0 + tid];
        linv[tid] = 1.0f / s;
    }
    __syncthreads();
    {
        const int c8 = (tid & 15) * 8, qg = tid >> 4;   // 16 q-groups x 2 q
        #pragma unroll
        for (int i = 0; i < 2; ++i) {
            const int q = qg * 2 + i;
            float s[8];
            #pragma unroll
            for (int k = 0; k < 8; ++k) s[k] = 0.f;
            for (int ch = 0; ch < nchunk; ++ch) {
                ushort8 p = *(const ushort8*)(Opart +
                    ((size_t)(ch * NB + b) * LQ + q0 + q) * CH + c8);
                #pragma unroll
                for (int k = 0; k < 8; ++k) s[k] += bf2f(p[k]);
            }
            const float li = linv[q];
            f32x4 o0, o1;
            #pragma unroll
            for (int k = 0; k < 4; ++k) { o0[k] = s[k] * li; o1[k] = s[k + 4] * li; }
            *(f32x4*)(ls + q * 132 + c8) = o0;
            *(f32x4*)(ls + q * 132 + c8 + 4) = o1;
        }
    }
    __syncthreads();
    {
        const int c = tid & 127, qh = tid >> 7;   // 2 halves of 16 q
        float* dst = out + ((size_t)b * CH + c) * LQ + q0 + qh * 16;
        #pragma unroll
        for (int i = 0; i < 4; ++i) {
            f32x4 o;
            #pragma unroll
            for (int r = 0; r < 4; ++r) o[r] = ls[(qh * 16 + i * 4 + r) * 132 + c];
            ((f32x4*)dst)[i] = o;
        }
    }
}

extern "C" void kernel_launch(void* const* d_in, const int* in_sizes, int n_in,
                              void* d_out, int out_size, void* d_ws, size_t ws_size,
                              hipStream_t stream) {
    const float* x   = (const float*)d_in[0];
    const float* Wkv = (const float*)d_in[1];
    const float* bkv = (const float*)d_in[2];
    float* out = (float*)d_out;

    const size_t vElems = (size_t)NB * LQ * CH;                 // 2M
    unsigned short* Vt = (unsigned short*)d_ws;                 // 4 MB
    unsigned short* Vc = Vt + vElems;                           // 4 MB
    float* Lsum = (float*)(Vc + vElems);                        // 512 KB (MAXCH)
    unsigned short* Opart = (unsigned short*)(Lsum + (size_t)MAXCH * NB * LQ);

    // nchunk=8 -> attn grid 1024 -> up to 3-4 blocks/CU resident
    int nchunk = MAXCH;
    const size_t fixed = 2 * vElems * 2 + (size_t)MAXCH * NB * LQ * 4;
    while (nchunk > 1 && fixed + (size_t)nchunk * NB * LQ * CH * 2 > ws_size) nchunk >>= 1;
    const int titers = (LQ / 64) / nchunk;

    prep_kernel<<<dim3(512), dim3(256), 0, stream>>>(x, Wkv, bkv, Vt, Vc);
    attn_kernel<<<dim3(128 * nchunk), dim3(256), 0, stream>>>(x, Vt, Vc, Opart, Lsum, titers);
    combine_kernel<<<dim3(512), dim3(256), 0, stream>>>(Opart, Lsum, out, nchunk);
}

// Round 6
// 135.707 us; speedup vs baseline: 1.8834x; 1.8834x over previous
//
#include <hip/hip_runtime.h>

#define LQ 4096
#define CH 128
#define NB 4
// log2(e)/sqrt(128): folded into Q so softmax = exp2(S)
#define QSCALE 0.12753139626233174f
#define ASTR 136    // tileA row stride (hw): 128 c + 8 pad
#define BSTR 72     // tileB row stride (hw): 64 t + 8 pad
#define MAXCH 8

#if defined(__has_builtin)
#if __has_builtin(__builtin_amdgcn_mfma_f32_16x16x16bf16_1k)
#define HAVE_MFMA16 1
#endif
#endif

typedef __attribute__((ext_vector_type(8))) unsigned short ushort8;
typedef __attribute__((ext_vector_type(4))) unsigned short ushort4v;
typedef __attribute__((ext_vector_type(4))) short short4v;
typedef __attribute__((ext_vector_type(8))) __bf16 bf16x8;
typedef __attribute__((ext_vector_type(4))) float f32x4;

__device__ inline unsigned short f2bf(float f) {
    unsigned int u = __builtin_bit_cast(unsigned int, f);
    u += 0x7fffu + ((u >> 16) & 1u);   // round-to-nearest-even
    return (unsigned short)(u >> 16);
}
__device__ inline float bf2f(unsigned short h) {
    unsigned int u = (unsigned int)h << 16;
    return __builtin_bit_cast(float, u);
}
// pack two positive floats to bf16 pair, round-half-up
__device__ inline unsigned int bfpack2(float a, float b) {
    unsigned int ua = __builtin_bit_cast(unsigned int, a) + 0x8000u;
    unsigned int ub = __builtin_bit_cast(unsigned int, b) + 0x8000u;
    return (ua >> 16) | (ub & 0xffff0000u);
}

// ---------------------------------------------------------------------------
// Kernel 1: v = W_kv @ x (+bias); emit bf16 Vt[b][t][c] and Vc[b][c][t].
// 512 blocks: (b, 64-l tile, o-half). W rows wave-uniform -> s_load broadcast.
// ---------------------------------------------------------------------------
__global__ __launch_bounds__(256) void prep_kernel(
    const float* __restrict__ x, const float* __restrict__ Wkv,
    const float* __restrict__ bkv,
    unsigned short* __restrict__ Vt, unsigned short* __restrict__ Vc)
{
    __shared__ unsigned short vs[64 * 64];   // [o_local][l] 8 KB
    const int tid = threadIdx.x;
    const int lane = tid & 63;
    const int b = blockIdx.x & 3;
    const int l0 = ((blockIdx.x >> 2) & 63) << 6;
    const int ohalf = blockIdx.x >> 8;              // 0/1
    const int o0l = __builtin_amdgcn_readfirstlane((tid >> 6) << 4);

    float xr[CH];   // x[:, l0+lane], coalesced loads
    #pragma unroll
    for (int c = 0; c < CH; ++c)
        xr[c] = x[((size_t)b * CH + c) * LQ + l0 + lane];

    for (int oo = 0; oo < 16; oo += 2) {
        const int ol = o0l + oo;
        const int o = ohalf * 64 + ol;
        const float* wr0 = Wkv + (size_t)o * CH;    // uniform -> s_load
        const float* wr1 = wr0 + CH;
        float p0[4] = {bkv[o], 0.f, 0.f, 0.f};
        float p1[4] = {bkv[o + 1], 0.f, 0.f, 0.f};
        #pragma unroll
        for (int c = 0; c < CH; c += 4) {
            #pragma unroll
            for (int k = 0; k < 4; ++k) {
                p0[k] += wr0[c + k] * xr[c + k];
                p1[k] += wr1[c + k] * xr[c + k];
            }
        }
        const float a0 = (p0[0] + p0[1]) + (p0[2] + p0[3]);
        const float a1 = (p1[0] + p1[1]) + (p1[2] + p1[3]);
        const unsigned short h0 = f2bf(a0), h1 = f2bf(a1);
        Vc[((size_t)b * CH + o) * LQ + l0 + lane] = h0;
        Vc[((size_t)b * CH + o + 1) * LQ + l0 + lane] = h1;
        vs[ol * 64 + lane] = h0;
        vs[(ol + 1) * 64 + lane] = h1;
    }
    __syncthreads();
    #pragma unroll
    for (int i = 0; i < 2; ++i) {
        const int idx = i * 256 + tid;        // l(64) x og(8)
        const int l = idx >> 3, og = idx & 7;
        ushort8 v;
        #pragma unroll
        for (int k = 0; k < 8; ++k) v[k] = vs[(og * 8 + k) * 64 + l];
        *(ushort8*)(Vt + ((size_t)b * LQ + l0 + l) * CH + ohalf * 64 + og * 8) = v;
    }
}

// ---------------------------------------------------------------------------
// Kernel 2: flash attention, split-K, LDS-staged tiles, transposed-S chain:
// S^T = mfma(A=V, B=Q) -> C-layout (q=l16, t=quad*4+r) -> exp2 -> feeds PV
// directly as the A-operand of mfma_f32_16x16x16_bf16 (k=quad*4+j matches).
// No P LDS round-trip. Register prefetch of next tile; launch_bounds(256,2)
// so nothing spills (r5 lesson: (256,3) forced 340 MB of scratch traffic).
// ---------------------------------------------------------------------------
__global__ __launch_bounds__(256, 2) void attn_kernel(
    const float* __restrict__ x, const unsigned short* __restrict__ Vt,
    const unsigned short* __restrict__ Vc,
    unsigned short* __restrict__ Opart, float* __restrict__ Lsum, int titers)
{
    __shared__ __align__(16) unsigned short tileA[64 * ASTR];      // 17408 B
    __shared__ __align__(16) unsigned short tileB[128 * BSTR];     // 18432 B
    const int tid = threadIdx.x;
    const int wave = tid >> 6, lane = tid & 63;
    const int quad = lane >> 4, l16 = lane & 15;
    const int b = blockIdx.x & 3;          // XCD k gets b = k%4 -> V L2-resident
    const int rest = blockIdx.x >> 2;
    const int qtile = rest & 31;           // 32 tiles of 128 q
    const int chunk = rest >> 5;
    const int q0w = (qtile << 7) + (wave << 5);
    const int tbase = chunk * titers * 64;

    const unsigned short* vtb = Vt + (size_t)b * LQ * CH;
    const unsigned short* vcb = Vc + (size_t)b * CH * LQ;

    // Q B-frags from x: B[n=l16 -> q][k=quad*8+j -> c], scaled (one-time)
    bf16x8 qf[2][4];
    #pragma unroll
    for (int mt = 0; mt < 2; ++mt)
        #pragma unroll
        for (int kc = 0; kc < 4; ++kc) {
            ushort8 v;
            #pragma unroll
            for (int j = 0; j < 8; ++j) {
                int c = kc * 32 + quad * 8 + j;
                v[j] = f2bf(x[((size_t)b * CH + c) * LQ + q0w + mt * 16 + l16] * QSCALE);
            }
            qf[mt][kc] = __builtin_bit_cast(bf16x8, v);
        }

    f32x4 oacc[2][8];
    #pragma unroll
    for (int mt = 0; mt < 2; ++mt)
        #pragma unroll
        for (int i = 0; i < 8; ++i) oacc[mt][i] = f32x4{0.f, 0.f, 0.f, 0.f};
    float lsum[2] = {0.f, 0.f};

    // prologue: prefetch tile 0 into registers (coalesced dwordx4)
    ushort8 RA[4], RB[4];
    {
        const int t0 = tbase;
        #pragma unroll
        for (int i = 0; i < 4; ++i) {
            const int ci = i * 256 + tid;
            RA[i] = *(const ushort8*)(vtb + (size_t)(t0 + (ci >> 4)) * CH + (ci & 15) * 8);
        }
        #pragma unroll
        for (int i = 0; i < 4; ++i) {
            const int ci = i * 256 + tid;
            RB[i] = *(const ushort8*)(vcb + (size_t)(ci >> 3) * LQ + t0 + (ci & 7) * 8);
        }
    }

    for (int it = 0; it < titers; ++it) {
        __syncthreads();   // all waves done reading LDS tiles (no-op at it=0)
        #pragma unroll
        for (int i = 0; i < 4; ++i) {
            const int ci = i * 256 + tid;
            *(ushort8*)(tileA + (ci >> 4) * ASTR + (ci & 15) * 8) = RA[i];
        }
        #pragma unroll
        for (int i = 0; i < 4; ++i) {
            const int ci = i * 256 + tid;
            *(ushort8*)(tileB + (ci >> 3) * BSTR + (ci & 7) * 8) = RB[i];
        }
        __syncthreads();   // staged tile visible
        // issue next-tile prefetch NOW (~full compute phase to cover latency)
        {
            const int t0n = (it + 1 < titers) ? tbase + (it + 1) * 64 : tbase;
            #pragma unroll
            for (int i = 0; i < 4; ++i) {
                const int ci = i * 256 + tid;
                RA[i] = *(const ushort8*)(vtb + (size_t)(t0n + (ci >> 4)) * CH + (ci & 15) * 8);
            }
            #pragma unroll
            for (int i = 0; i < 4; ++i) {
                const int ci = i * 256 + tid;
                RB[i] = *(const ushort8*)(vcb + (size_t)(ci >> 3) * LQ + t0n + (ci & 7) * 8);
            }
        }
        // per 16-key sub-tile nt: S^T -> exp2 -> PV (P stays in registers)
        #pragma unroll
        for (int nt = 0; nt < 4; ++nt) {
            // A-frags: V[t=nt*16+l16][c=kc*32+quad*8+j] from tileA (b128)
            bf16x8 vA[4];
            #pragma unroll
            for (int kc = 0; kc < 4; ++kc)
                vA[kc] = __builtin_bit_cast(bf16x8,
                    *(const ushort8*)(tileA + (nt * 16 + l16) * ASTR + kc * 32 + quad * 8));
            // S^T tiles: D[m=t][n=q]; lane: q=l16, t=nt*16+quad*4+r
            f32x4 s[2];
            #pragma unroll
            for (int mt = 0; mt < 2; ++mt) {
                s[mt] = f32x4{0.f, 0.f, 0.f, 0.f};
                #pragma unroll
                for (int kc = 0; kc < 4; ++kc)
                    s[mt] = __builtin_amdgcn_mfma_f32_16x16x32_bf16(vA[kc], qf[mt][kc], s[mt], 0, 0, 0);
            }
            // exp2 + pack P as PV A-operand (k = quad*4 + j matches t layout)
#ifdef HAVE_MFMA16
            short4v pf[2];
#else
            bf16x8 pf[2];
#endif
            #pragma unroll
            for (int mt = 0; mt < 2; ++mt) {
                float p0 = __builtin_amdgcn_exp2f(s[mt][0]);
                float p1 = __builtin_amdgcn_exp2f(s[mt][1]);
                float p2 = __builtin_amdgcn_exp2f(s[mt][2]);
                float p3 = __builtin_amdgcn_exp2f(s[mt][3]);
                lsum[mt] += (p0 + p1) + (p2 + p3);
                unsigned int lo = bfpack2(p0, p1);
                unsigned int hi = bfpack2(p2, p3);
#ifdef HAVE_MFMA16
                ushort4v pk;
                pk[0] = (unsigned short)lo; pk[1] = (unsigned short)(lo >> 16);
                pk[2] = (unsigned short)hi; pk[3] = (unsigned short)(hi >> 16);
                pf[mt] = __builtin_bit_cast(short4v, pk);
#else
                ushort8 pk;
                pk[0] = (unsigned short)lo; pk[1] = (unsigned short)(lo >> 16);
                pk[2] = (unsigned short)hi; pk[3] = (unsigned short)(hi >> 16);
                pk[4] = 0; pk[5] = 0; pk[6] = 0; pk[7] = 0;
                pf[mt] = __builtin_bit_cast(bf16x8, pk);
#endif
            }
            // PV: B[k=quad*4+j][n=c=l16] = V[t=nt*16+quad*4+j][c] (b64 reads)
            #pragma unroll
            for (int nc = 0; nc < 8; ++nc) {
                ushort4v d = *(const ushort4v*)(tileB +
                    (nc * 16 + l16) * BSTR + nt * 16 + quad * 4);
#ifdef HAVE_MFMA16
                short4v vB = __builtin_bit_cast(short4v, d);
                #pragma unroll
                for (int mt = 0; mt < 2; ++mt)
                    oacc[mt][nc] = __builtin_amdgcn_mfma_f32_16x16x16bf16_1k(
                        pf[mt], vB, oacc[mt][nc], 0, 0, 0);
#else
                ushort8 vb;
                vb[0] = d[0]; vb[1] = d[1]; vb[2] = d[2]; vb[3] = d[3];
                vb[4] = 0; vb[5] = 0; vb[6] = 0; vb[7] = 0;
                bf16x8 vB = __builtin_bit_cast(bf16x8, vb);
                #pragma unroll
                for (int mt = 0; mt < 2; ++mt)
                    oacc[mt][nc] = __builtin_amdgcn_mfma_f32_16x16x32_bf16(
                        pf[mt], vB, oacc[mt][nc], 0, 0, 0);
#endif
            }
        }
    }
    // ---- Lsum: reduce per-lane partial (q=l16) across the 4 quads ----
    const size_t pbase = ((size_t)(chunk * NB + b) * LQ);
    #pragma unroll
    for (int mt = 0; mt < 2; ++mt) {
        float v = lsum[mt];
        v += __shfl_xor(v, 16);
        v += __shfl_xor(v, 32);
        if (lane < 16) Lsum[pbase + q0w + mt * 16 + lane] = v;
    }
    // ---- write partials: Opart[ch][b][q][c] (bf16); oacc lane: q=quad*4+r, c=l16
    #pragma unroll
    for (int mt = 0; mt < 2; ++mt)
        #pragma unroll
        for (int r = 0; r < 4; ++r) {
            const int q = q0w + mt * 16 + quad * 4 + r;
            unsigned short* orow = Opart + (pbase + q) * CH + l16;
            #pragma unroll
            for (int nc = 0; nc < 8; ++nc) orow[nc * 16] = f2bf(oacc[mt][nc][r]);
        }
}

// ---------------------------------------------------------------------------
// Kernel 3: out[b][c][q] = sum_ch Opart[ch][b][q][c] / sum_ch Lsum[ch][b][q]
// 512 blocks: (b, 32-q tile). LDS transpose.
// ---------------------------------------------------------------------------
__global__ __launch_bounds__(256) void combine_kernel(
    const unsigned short* __restrict__ Opart, const float* __restrict__ Lsum,
    float* __restrict__ out, int nchunk)
{
    __shared__ __align__(16) float ls[32 * 132];   // [q][c] padded
    __shared__ float linv[32];
    const int tid = threadIdx.x;
    const int b = blockIdx.x & 3;
    const int q0 = (blockIdx.x >> 2) << 5;

    if (tid < 32) {
        float s = 0.f;
        for (int ch = 0; ch < nchunk; ++ch) s += Lsum[(size_t)(ch * NB + b) * LQ + q0 + tid];
        linv[tid] = 1.0f / s;
    }
    __syncthreads();
    {
        const int c8 = (tid & 15) * 8, qg = tid >> 4;   // 16 q-groups x 2 q
        #pragma unroll
        for (int i = 0; i < 2; ++i) {
            const int q = qg * 2 + i;
            float s[8];
            #pragma unroll
            for (int k = 0; k < 8; ++k) s[k] = 0.f;
            for (int ch = 0; ch < nchunk; ++ch) {
                ushort8 p = *(const ushort8*)(Opart +
                    ((size_t)(ch * NB + b) * LQ + q0 + q) * CH + c8);
                #pragma unroll
                for (int k = 0; k < 8; ++k) s[k] += bf2f(p[k]);
            }
            const float li = linv[q];
            f32x4 o0, o1;
            #pragma unroll
            for (int k = 0; k < 4; ++k) { o0[k] = s[k] * li; o1[k] = s[k + 4] * li; }
            *(f32x4*)(ls + q * 132 + c8) = o0;
            *(f32x4*)(ls + q * 132 + c8 + 4) = o1;
        }
    }
    __syncthreads();
    {
        const int c = tid & 127, qh = tid >> 7;   // 2 halves of 16 q
        float* dst = out + ((size_t)b * CH + c) * LQ + q0 + qh * 16;
        #pragma unroll
        for (int i = 0; i < 4; ++i) {
            f32x4 o;
            #pragma unroll
            for (int r = 0; r < 4; ++r) o[r] = ls[(qh * 16 + i * 4 + r) * 132 + c];
            ((f32x4*)dst)[i] = o;
        }
    }
}

extern "C" void kernel_launch(void* const* d_in, const int* in_sizes, int n_in,
                              void* d_out, int out_size, void* d_ws, size_t ws_size,
                              hipStream_t stream) {
    const float* x   = (const float*)d_in[0];
    const float* Wkv = (const float*)d_in[1];
    const float* bkv = (const float*)d_in[2];
    float* out = (float*)d_out;

    const size_t vElems = (size_t)NB * LQ * CH;                 // 2M
    unsigned short* Vt = (unsigned short*)d_ws;                 // 4 MB
    unsigned short* Vc = Vt + vElems;                           // 4 MB
    float* Lsum = (float*)(Vc + vElems);                        // 512 KB (MAXCH)
    unsigned short* Opart = (unsigned short*)(Lsum + (size_t)MAXCH * NB * LQ);

    // nchunk=4 -> attn grid 512 = exactly 2 blocks/CU resident
    int nchunk = 4;
    const size_t fixed = 2 * vElems * 2 + (size_t)MAXCH * NB * LQ * 4;
    while (nchunk > 1 && fixed + (size_t)nchunk * NB * LQ * CH * 2 > ws_size) nchunk >>= 1;
    const int titers = (LQ / 64) / nchunk;

    prep_kernel<<<dim3(512), dim3(256), 0, stream>>>(x, Wkv, bkv, Vt, Vc);
    attn_kernel<<<dim3(128 * nchunk), dim3(256), 0, stream>>>(x, Vt, Vc, Opart, Lsum, titers);
    combine_kernel<<<dim3(512), dim3(256), 0, stream>>>(Opart, Lsum, out, nchunk);
}

// Round 7
// 131.355 us; speedup vs baseline: 1.9458x; 1.0331x over previous
//
#include <hip/hip_runtime.h>

#define LQ 4096
#define CH 128
#define NB 4
// log2(e)/sqrt(128): folded into Q so softmax = exp2(S)
#define QSCALE 0.12753139626233174f
#define ASTR 136    // tileA row stride (hw): 128 c + 8 pad
#define BSTR 72     // tileB row stride (hw): 64 t + 8 pad
#define MAXCH 8

#if defined(__has_builtin)
#if __has_builtin(__builtin_amdgcn_mfma_f32_16x16x16bf16_1k)
#define HAVE_MFMA16 1
#endif
#endif

typedef __attribute__((ext_vector_type(8))) unsigned short ushort8;
typedef __attribute__((ext_vector_type(4))) unsigned short ushort4v;
typedef __attribute__((ext_vector_type(4))) short short4v;
typedef __attribute__((ext_vector_type(8))) __bf16 bf16x8;
typedef __attribute__((ext_vector_type(4))) float f32x4;

__device__ inline unsigned short f2bf(float f) {
    unsigned int u = __builtin_bit_cast(unsigned int, f);
    u += 0x7fffu + ((u >> 16) & 1u);   // round-to-nearest-even
    return (unsigned short)(u >> 16);
}
__device__ inline float bf2f(unsigned short h) {
    unsigned int u = (unsigned int)h << 16;
    return __builtin_bit_cast(float, u);
}
// pack two positive floats to bf16 pair, round-half-up
__device__ inline unsigned int bfpack2(float a, float b) {
    unsigned int ua = __builtin_bit_cast(unsigned int, a) + 0x8000u;
    unsigned int ub = __builtin_bit_cast(unsigned int, b) + 0x8000u;
    return (ua >> 16) | (ub & 0xffff0000u);
}

// ---------------------------------------------------------------------------
// Kernel 1 (MFMA rewrite): v = W_kv @ x (+bias); emit bf16 Vt[b][t][c] and
// Vc[b][c][t]. 256 blocks: (b, 64-l tile). Wave w: o in [w*32, w*32+32),
// all 64 l; 32 MFMAs (16x16x32 bf16, K=128). Epilogue via padded LDS ->
// fully-coalesced ushort8 stores of Vc and Vt.
// ---------------------------------------------------------------------------
__global__ __launch_bounds__(256) void prep_kernel(
    const float* __restrict__ x, const float* __restrict__ Wkv,
    const float* __restrict__ bkv,
    unsigned short* __restrict__ Vt, unsigned short* __restrict__ Vc)
{
    __shared__ __align__(16) unsigned short xs[64 * 136];  // [l][c] bf16, 17 KB
    __shared__ __align__(16) unsigned short vs[128 * 72];  // [o][l] bf16, 18 KB
    const int tid = threadIdx.x;
    const int lane = tid & 63;
    const int wave = tid >> 6;
    const int quad = lane >> 4, l16 = lane & 15;
    const int b = blockIdx.x & 3;
    const int l0 = (blockIdx.x >> 2) << 6;

    {   // stage x tile transposed: [64 l][128 c] bf16 (coalesced f32x4 loads)
        const f32x4* xg4 = (const f32x4*)(x + (size_t)b * CH * LQ + l0);
        #pragma unroll
        for (int i = 0; i < 8; ++i) {
            int idx = i * 256 + tid;          // 2048 chunks: c(128) x l4(16)
            int c = idx >> 4, l4 = idx & 15;
            f32x4 v = xg4[c * (LQ / 4) + l4];
            #pragma unroll
            for (int m = 0; m < 4; ++m) xs[(l4 * 4 + m) * 136 + c] = f2bf(v[m]);
        }
    }
    __syncthreads();

    const int wo = wave * 32;
    f32x4 acc[2][4];   // [ot][lt]
    #pragma unroll
    for (int ot = 0; ot < 2; ++ot)
        #pragma unroll
        for (int lt = 0; lt < 4; ++lt) acc[ot][lt] = f32x4{0.f, 0.f, 0.f, 0.f};

    #pragma unroll
    for (int kc = 0; kc < 4; ++kc) {
        // A-frags: W[o=wo+ot*16+l16][c=kc*32+quad*8+j], fp32->bf16 inline
        bf16x8 af[2];
        #pragma unroll
        for (int ot = 0; ot < 2; ++ot) {
            const float* wrow = Wkv + (size_t)(wo + ot * 16 + l16) * CH + kc * 32 + quad * 8;
            ushort8 a;
            #pragma unroll
            for (int j = 0; j < 8; ++j) a[j] = f2bf(wrow[j]);
            af[ot] = __builtin_bit_cast(bf16x8, a);
        }
        // B-frags: X[l=lt*16+l16][c=kc*32+quad*8+j] from xs (b128)
        #pragma unroll
        for (int lt = 0; lt < 4; ++lt) {
            bf16x8 bf = __builtin_bit_cast(bf16x8,
                *(const ushort8*)(xs + (lt * 16 + l16) * 136 + kc * 32 + quad * 8));
            #pragma unroll
            for (int ot = 0; ot < 2; ++ot)
                acc[ot][lt] = __builtin_amdgcn_mfma_f32_16x16x32_bf16(af[ot], bf, acc[ot][lt], 0, 0, 0);
        }
    }
    // bias + stage to vs[o][l] (C-layout: o = wo+ot*16+quad*4+r, l = lt*16+l16)
    #pragma unroll
    for (int ot = 0; ot < 2; ++ot) {
        float bias[4];
        #pragma unroll
        for (int r = 0; r < 4; ++r) bias[r] = bkv[wo + ot * 16 + quad * 4 + r];
        #pragma unroll
        for (int lt = 0; lt < 4; ++lt)
            #pragma unroll
            for (int r = 0; r < 4; ++r)
                vs[(wo + ot * 16 + quad * 4 + r) * 72 + lt * 16 + l16] =
                    f2bf(acc[ot][lt][r] + bias[r]);
    }
    __syncthreads();
    // Vc[b][o][l0..l0+64): 1024 chunks o(128) x l8(8), coalesced 16B stores
    #pragma unroll
    for (int i = 0; i < 4; ++i) {
        const int chunk = i * 256 + tid;
        const int o = chunk >> 3, l8 = chunk & 7;
        *(ushort8*)(Vc + ((size_t)b * CH + o) * LQ + l0 + l8 * 8) =
            *(const ushort8*)(vs + o * 72 + l8 * 8);
    }
    // Vt[b][l0+l][og*8..+8): 1024 chunks l(64) x og(16), coalesced 16B stores
    #pragma unroll
    for (int i = 0; i < 4; ++i) {
        const int chunk = i * 256 + tid;
        const int l = chunk >> 4, og = chunk & 15;
        ushort8 v;
        #pragma unroll
        for (int k = 0; k < 8; ++k) v[k] = vs[(og * 8 + k) * 72 + l];
        *(ushort8*)(Vt + ((size_t)b * LQ + l0 + l) * CH + og * 8) = v;
    }
}

// ---------------------------------------------------------------------------
// Kernel 2: flash attention, split-K (nchunk=8 -> grid 1024 = 4 blocks/CU),
// LDS-staged tiles, transposed-S chain: S^T = mfma(A=V, B=Q) -> exp2 -> feeds
// PV directly as A-operand of mfma_f32_16x16x16_bf16. No P LDS round-trip.
// Inner loop identical to round 6 (verified); only the chunk count changed.
// ---------------------------------------------------------------------------
__global__ __launch_bounds__(256, 2) void attn_kernel(
    const float* __restrict__ x, const unsigned short* __restrict__ Vt,
    const unsigned short* __restrict__ Vc,
    unsigned short* __restrict__ Opart, float* __restrict__ Lsum, int titers)
{
    __shared__ __align__(16) unsigned short tileA[64 * ASTR];      // 17408 B
    __shared__ __align__(16) unsigned short tileB[128 * BSTR];     // 18432 B
    const int tid = threadIdx.x;
    const int wave = tid >> 6, lane = tid & 63;
    const int quad = lane >> 4, l16 = lane & 15;
    const int b = blockIdx.x & 3;          // bid%8 -> fixed b per XCD (L2 locality)
    const int rest = blockIdx.x >> 2;
    const int qtile = rest & 31;           // 32 tiles of 128 q
    const int chunk = rest >> 5;
    const int q0w = (qtile << 7) + (wave << 5);
    const int tbase = chunk * titers * 64;

    const unsigned short* vtb = Vt + (size_t)b * LQ * CH;
    const unsigned short* vcb = Vc + (size_t)b * CH * LQ;

    // Q B-frags from x: B[n=l16 -> q][k=quad*8+j -> c], scaled (one-time)
    bf16x8 qf[2][4];
    #pragma unroll
    for (int mt = 0; mt < 2; ++mt)
        #pragma unroll
        for (int kc = 0; kc < 4; ++kc) {
            ushort8 v;
            #pragma unroll
            for (int j = 0; j < 8; ++j) {
                int c = kc * 32 + quad * 8 + j;
                v[j] = f2bf(x[((size_t)b * CH + c) * LQ + q0w + mt * 16 + l16] * QSCALE);
            }
            qf[mt][kc] = __builtin_bit_cast(bf16x8, v);
        }

    f32x4 oacc[2][8];
    #pragma unroll
    for (int mt = 0; mt < 2; ++mt)
        #pragma unroll
        for (int i = 0; i < 8; ++i) oacc[mt][i] = f32x4{0.f, 0.f, 0.f, 0.f};
    float lsum[2] = {0.f, 0.f};

    // prologue: prefetch tile 0 into registers (coalesced dwordx4)
    ushort8 RA[4], RB[4];
    {
        const int t0 = tbase;
        #pragma unroll
        for (int i = 0; i < 4; ++i) {
            const int ci = i * 256 + tid;
            RA[i] = *(const ushort8*)(vtb + (size_t)(t0 + (ci >> 4)) * CH + (ci & 15) * 8);
        }
        #pragma unroll
        for (int i = 0; i < 4; ++i) {
            const int ci = i * 256 + tid;
            RB[i] = *(const ushort8*)(vcb + (size_t)(ci >> 3) * LQ + t0 + (ci & 7) * 8);
        }
    }

    for (int it = 0; it < titers; ++it) {
        __syncthreads();   // all waves done reading LDS tiles (no-op at it=0)
        #pragma unroll
        for (int i = 0; i < 4; ++i) {
            const int ci = i * 256 + tid;
            *(ushort8*)(tileA + (ci >> 4) * ASTR + (ci & 15) * 8) = RA[i];
        }
        #pragma unroll
        for (int i = 0; i < 4; ++i) {
            const int ci = i * 256 + tid;
            *(ushort8*)(tileB + (ci >> 3) * BSTR + (ci & 7) * 8) = RB[i];
        }
        __syncthreads();   // staged tile visible
        // issue next-tile prefetch NOW (~full compute phase to cover latency)
        {
            const int t0n = (it + 1 < titers) ? tbase + (it + 1) * 64 : tbase;
            #pragma unroll
            for (int i = 0; i < 4; ++i) {
                const int ci = i * 256 + tid;
                RA[i] = *(const ushort8*)(vtb + (size_t)(t0n + (ci >> 4)) * CH + (ci & 15) * 8);
            }
            #pragma unroll
            for (int i = 0; i < 4; ++i) {
                const int ci = i * 256 + tid;
                RB[i] = *(const ushort8*)(vcb + (size_t)(ci >> 3) * LQ + t0n + (ci & 7) * 8);
            }
        }
        // per 16-key sub-tile nt: S^T -> exp2 -> PV (P stays in registers)
        #pragma unroll
        for (int nt = 0; nt < 4; ++nt) {
            // A-frags: V[t=nt*16+l16][c=kc*32+quad*8+j] from tileA (b128)
            bf16x8 vA[4];
            #pragma unroll
            for (int kc = 0; kc < 4; ++kc)
                vA[kc] = __builtin_bit_cast(bf16x8,
                    *(const ushort8*)(tileA + (nt * 16 + l16) * ASTR + kc * 32 + quad * 8));
            // S^T tiles: D[m=t][n=q]; lane: q=l16, t=nt*16+quad*4+r
            f32x4 s[2];
            #pragma unroll
            for (int mt = 0; mt < 2; ++mt) {
                s[mt] = f32x4{0.f, 0.f, 0.f, 0.f};
                #pragma unroll
                for (int kc = 0; kc < 4; ++kc)
                    s[mt] = __builtin_amdgcn_mfma_f32_16x16x32_bf16(vA[kc], qf[mt][kc], s[mt], 0, 0, 0);
            }
            // exp2 + pack P as PV A-operand (k = quad*4 + j matches t layout)
#ifdef HAVE_MFMA16
            short4v pf[2];
#else
            bf16x8 pf[2];
#endif
            #pragma unroll
            for (int mt = 0; mt < 2; ++mt) {
                float p0 = __builtin_amdgcn_exp2f(s[mt][0]);
                float p1 = __builtin_amdgcn_exp2f(s[mt][1]);
                float p2 = __builtin_amdgcn_exp2f(s[mt][2]);
                float p3 = __builtin_amdgcn_exp2f(s[mt][3]);
                lsum[mt] += (p0 + p1) + (p2 + p3);
                unsigned int lo = bfpack2(p0, p1);
                unsigned int hi = bfpack2(p2, p3);
#ifdef HAVE_MFMA16
                ushort4v pk;
                pk[0] = (unsigned short)lo; pk[1] = (unsigned short)(lo >> 16);
                pk[2] = (unsigned short)hi; pk[3] = (unsigned short)(hi >> 16);
                pf[mt] = __builtin_bit_cast(short4v, pk);
#else
                ushort8 pk;
                pk[0] = (unsigned short)lo; pk[1] = (unsigned short)(lo >> 16);
                pk[2] = (unsigned short)hi; pk[3] = (unsigned short)(hi >> 16);
                pk[4] = 0; pk[5] = 0; pk[6] = 0; pk[7] = 0;
                pf[mt] = __builtin_bit_cast(bf16x8, pk);
#endif
            }
            // PV: B[k=quad*4+j][n=c=l16] = V[t=nt*16+quad*4+j][c] (b64 reads)
            #pragma unroll
            for (int nc = 0; nc < 8; ++nc) {
                ushort4v d = *(const ushort4v*)(tileB +
                    (nc * 16 + l16) * BSTR + nt * 16 + quad * 4);
#ifdef HAVE_MFMA16
                short4v vB = __builtin_bit_cast(short4v, d);
                #pragma unroll
                for (int mt = 0; mt < 2; ++mt)
                    oacc[mt][nc] = __builtin_amdgcn_mfma_f32_16x16x16bf16_1k(
                        pf[mt], vB, oacc[mt][nc], 0, 0, 0);
#else
                ushort8 vb;
                vb[0] = d[0]; vb[1] = d[1]; vb[2] = d[2]; vb[3] = d[3];
                vb[4] = 0; vb[5] = 0; vb[6] = 0; vb[7] = 0;
                bf16x8 vB = __builtin_bit_cast(bf16x8, vb);
                #pragma unroll
                for (int mt = 0; mt < 2; ++mt)
                    oacc[mt][nc] = __builtin_amdgcn_mfma_f32_16x16x32_bf16(
                        pf[mt], vB, oacc[mt][nc], 0, 0, 0);
#endif
            }
        }
    }
    // ---- Lsum: reduce per-lane partial (q=l16) across the 4 quads ----
    const size_t pbase = ((size_t)(chunk * NB + b) * LQ);
    #pragma unroll
    for (int mt = 0; mt < 2; ++mt) {
        float v = lsum[mt];
        v += __shfl_xor(v, 16);
        v += __shfl_xor(v, 32);
        if (lane < 16) Lsum[pbase + q0w + mt * 16 + lane] = v;
    }
    // ---- write partials: Opart[ch][b][q][c] (bf16); oacc lane: q=quad*4+r, c=l16
    #pragma unroll
    for (int mt = 0; mt < 2; ++mt)
        #pragma unroll
        for (int r = 0; r < 4; ++r) {
            const int q = q0w + mt * 16 + quad * 4 + r;
            unsigned short* orow = Opart + (pbase + q) * CH + l16;
            #pragma unroll
            for (int nc = 0; nc < 8; ++nc) orow[nc * 16] = f2bf(oacc[mt][nc][r]);
        }
}

// ---------------------------------------------------------------------------
// Kernel 3: out[b][c][q] = sum_ch Opart[ch][b][q][c] / sum_ch Lsum[ch][b][q]
// 512 blocks: (b, 32-q tile). LDS transpose.
// ---------------------------------------------------------------------------
__global__ __launch_bounds__(256) void combine_kernel(
    const unsigned short* __restrict__ Opart, const float* __restrict__ Lsum,
    float* __restrict__ out, int nchunk)
{
    __shared__ __align__(16) float ls[32 * 132];   // [q][c] padded
    __shared__ float linv[32];
    const int tid = threadIdx.x;
    const int b = blockIdx.x & 3;
    const int q0 = (blockIdx.x >> 2) << 5;

    if (tid < 32) {
        float s = 0.f;
        for (int ch = 0; ch < nchunk; ++ch) s += Lsum[(size_t)(ch * NB + b) * LQ + q0 + tid];
        linv[tid] = 1.0f / s;
    }
    __syncthreads();
    {
        const int c8 = (tid & 15) * 8, qg = tid >> 4;   // 16 q-groups x 2 q
        #pragma unroll
        for (int i = 0; i < 2; ++i) {
            const int q = qg * 2 + i;
            float s[8];
            #pragma unroll
            for (int k = 0; k < 8; ++k) s[k] = 0.f;
            for (int ch = 0; ch < nchunk; ++ch) {
                ushort8 p = *(const ushort8*)(Opart +
                    ((size_t)(ch * NB + b) * LQ + q0 + q) * CH + c8);
                #pragma unroll
                for (int k = 0; k < 8; ++k) s[k] += bf2f(p[k]);
            }
            const float li = linv[q];
            f32x4 o0, o1;
            #pragma unroll
            for (int k = 0; k < 4; ++k) { o0[k] = s[k] * li; o1[k] = s[k + 4] * li; }
            *(f32x4*)(ls + q * 132 + c8) = o0;
            *(f32x4*)(ls + q * 132 + c8 + 4) = o1;
        }
    }
    __syncthreads();
    {
        const int c = tid & 127, qh = tid >> 7;   // 2 halves of 16 q
        float* dst = out + ((size_t)b * CH + c) * LQ + q0 + qh * 16;
        #pragma unroll
        for (int i = 0; i < 4; ++i) {
            f32x4 o;
            #pragma unroll
            for (int r = 0; r < 4; ++r) o[r] = ls[(qh * 16 + i * 4 + r) * 132 + c];
            ((f32x4*)dst)[i] = o;
        }
    }
}

extern "C" void kernel_launch(void* const* d_in, const int* in_sizes, int n_in,
                              void* d_out, int out_size, void* d_ws, size_t ws_size,
                              hipStream_t stream) {
    const float* x   = (const float*)d_in[0];
    const float* Wkv = (const float*)d_in[1];
    const float* bkv = (const float*)d_in[2];
    float* out = (float*)d_out;

    const size_t vElems = (size_t)NB * LQ * CH;                 // 2M
    unsigned short* Vt = (unsigned short*)d_ws;                 // 4 MB
    unsigned short* Vc = Vt + vElems;                           // 4 MB
    float* Lsum = (float*)(Vc + vElems);                        // 512 KB (MAXCH)
    unsigned short* Opart = (unsigned short*)(Lsum + (size_t)MAXCH * NB * LQ);

    // nchunk=8 -> attn grid 1024 = exactly 4 blocks/CU resident
    int nchunk = MAXCH;
    const size_t fixed = 2 * vElems * 2 + (size_t)MAXCH * NB * LQ * 4;
    while (nchunk > 1 && fixed + (size_t)nchunk * NB * LQ * CH * 2 > ws_size) nchunk >>= 1;
    const int titers = (LQ / 64) / nchunk;

    prep_kernel<<<dim3(256), dim3(256), 0, stream>>>(x, Wkv, bkv, Vt, Vc);
    attn_kernel<<<dim3(128 * nchunk), dim3(256), 0, stream>>>(x, Vt, Vc, Opart, Lsum, titers);
    combine_kernel<<<dim3(512), dim3(256), 0, stream>>>(Opart, Lsum, out, nchunk);
}